// Round 3
// baseline (9782.490 us; speedup 1.0000x reference)
//
#include <hip/hip_runtime.h>

// ---------------- problem constants ----------------
#define T_STEPS 256
#define BATCH   64
#define DIN     512
#define HID     1024
#define NCOLS   4096   // 4*HID
#define NBLK    256    // persistent blocks (1 per CU)
#define TPB     256    // 4 waves

typedef __attribute__((ext_vector_type(8))) short short8;
typedef __attribute__((ext_vector_type(4))) float float4v;
typedef unsigned long long u64;

union Frag { u64 u[2]; short8 s; };

__device__ __forceinline__ short f2bf(float x) {
    unsigned u = __float_as_uint(x);
    u += 0x7FFFu + ((u >> 16) & 1u);   // RNE
    return (short)(u >> 16);
}
__device__ __forceinline__ float sigmoidf_(float x) { return 1.0f / (1.0f + __expf(-x)); }
__device__ __forceinline__ float tanhf_(float x)    { return 1.0f - 2.0f / (__expf(2.0f * x) + 1.0f); }

// ---------------- prologue kernels ----------------
__global__ void cvt_bf16_kernel(const float* __restrict__ src, short* __restrict__ dst, int n) {
    int i = blockIdx.x * blockDim.x + threadIdx.x;
    int stride = gridDim.x * blockDim.x;
    for (; i < n; i += stride) dst[i] = f2bf(src[i]);
}

// src: R x C fp32 row-major -> dst: C x R bf16 row-major
__global__ void transpose_bf16_kernel(const float* __restrict__ src, short* __restrict__ dst,
                                      int R, int C) {
    __shared__ float tile[32][33];
    int tx = threadIdx.x, ty = threadIdx.y;
    int r0 = blockIdx.y * 32, c0 = blockIdx.x * 32;
#pragma unroll
    for (int i = 0; i < 32; i += 8)
        tile[ty + i][tx] = src[(size_t)(r0 + ty + i) * C + (c0 + tx)];
    __syncthreads();
#pragma unroll
    for (int i = 0; i < 32; i += 8)
        dst[(size_t)(c0 + ty + i) * R + (r0 + tx)] = f2bf(tile[tx][ty + i]);
}

// ---------------- fused persistent LSTM, layer-pipelined ----------------
// Superstep s (0..256): layer0 computes t0=s, layer1 computes t1=s-1.
// One grid barrier per superstep (257 instead of 512).
//
// Communication substrate = byte-for-byte the proven 7.3ms kernel's:
//  - h state in parity double-buffers (h0A/B, h1A/B, 128 KB each), zeroed by
//    memset before launch (gives correct h(-1)=0 -> BN(0)=beta boundary).
//  - writes: relaxed AGENT-scope atomic stores (sc0 sc1 -> coherence point),
//    drained with s_waitcnt(0) + __syncthreads before the flag store.
//  - reads: relaxed AGENT-scope atomic loads (bypass L1/L2).
//  - parity (p = s&1): read h0(s-1) from buf0[1-p], write h0(s) to buf0[p];
//    read h1(s-2) from buf1[p], write h1(s-1) to buf1[1-p]. Disjoint within
//    a superstep; barrier-separated across supersteps.
//  - A2 = h0(s-1) feeds BOTH hh0 (layer0 recurrence) and ih1 (layer1 input):
//    one bypass load stream, two MFMA streams.
//  - read-only data (xb, all 4 transposed weight buffers) via normal cached
//    loads (written by prologue dispatches; dispatch-boundary flush).
// Workspace footprint 46.7 MB -- well inside the proven 80.2 MB budget
// (rounds 1-2 failed with deterministic garbage at offsets > 80 MB).
__global__ __launch_bounds__(TPB, 1) void lstm_persist(
    const int* __restrict__ length,
    const float* __restrict__ b0,  const float* __restrict__ g_ih0, const float* __restrict__ bt_ih0,
    const float* __restrict__ g_hh0, const float* __restrict__ bt_hh0,
    const float* __restrict__ g_c0,  const float* __restrict__ bt_c0,
    const float* __restrict__ b1,  const float* __restrict__ g_ih1, const float* __restrict__ bt_ih1,
    const float* __restrict__ g_hh1, const float* __restrict__ bt_hh1,
    const float* __restrict__ g_c1,  const float* __restrict__ bt_c1,
    const short* __restrict__ xb,
    const short* __restrict__ wih0T, const short* __restrict__ whh0T,
    const short* __restrict__ wih1T, const short* __restrict__ whh1T,
    short* __restrict__ h0A, short* __restrict__ h0B,
    short* __restrict__ h1A, short* __restrict__ h1B,
    unsigned* __restrict__ flags,
    float* __restrict__ out)
{
    const int wg   = blockIdx.x;
    const int tid  = threadIdx.x;
    const int wave = tid >> 6;
    const int lane = tid & 63;
    const int nidx = lane & 15;
    const int quad = lane >> 4;

    __shared__ float st_s[4][16][17];   // per-wave 16x16 s tile (+pad)
    __shared__ float red_h[4][16][2];   // per-wave column (sum,sumsq) hh
    __shared__ float red_i[4][16][2];   // ... ih
    __shared__ float red_c[4][4][2];    // per-wave (sum,sumsq) for c, 4 j's
    __shared__ unsigned okv[4];         // barrier poll combine

    const int jj   = nidx & 3;
    const int gidx = nidx >> 2;
    const int ncol = wg * 4 + jj + gidx * HID;   // s-space column 0..4095
    const int m_row = wave * 16 + nidx;          // A-fragment batch row

    const int mc   = lane & 15;                  // c-phase: row within wave
    const int jc   = quad;                       // c-phase: which of 4 j's
    const int m_cg = wave * 16 + mc;
    const int j_g  = wg * 4 + jc;
    const int len_c = length[m_cg];
    const float inv64 = 1.0f / 64.0f;

    // per-layer BN / bias params (registers for the whole run)
    const float gih0v = g_ih0[ncol], btih0v = bt_ih0[ncol];
    const float ghh0v = g_hh0[ncol], bthh0v = bt_hh0[ncol], bb0v = b0[ncol];
    const float gc0v  = g_c0[j_g],   btc0v  = bt_c0[j_g];
    const float gih1v = g_ih1[ncol], btih1v = bt_ih1[ncol];
    const float ghh1v = g_hh1[ncol], bthh1v = bt_hh1[ncol], bb1v = b1[ncol];
    const float gc1v  = g_c1[j_g],   btc1v  = bt_c1[j_g];

    // B-fragment base pointers (cached, read-only; L2-resident per XCD)
    const short8* Bi0p = (const short8*)wih0T + (size_t)ncol * (DIN / 8) + quad;
    const short8* Bh0p = (const short8*)whh0T + (size_t)ncol * (HID / 8) + quad;
    const short8* Bi1p = (const short8*)wih1T + (size_t)ncol * (HID / 8) + quad;
    const short8* Bh1p = (const short8*)whh1T + (size_t)ncol * (HID / 8) + quad;

    float h0_st = 0.f, c0_st = 0.f, h1_st = 0.f, c1_st = 0.f;

#pragma unroll 1
    for (int s = 0; s <= T_STEPS; ++s) {
        const bool do0 = (s < T_STEPS);   // layer0 active (t0 = s)
        const bool do1 = (s >= 1);        // layer1 active (t1 = s-1)
        const int t0 = s, t1 = s - 1;
        const int p  = s & 1;
        const short* h0r = p ? h0A : h0B;   // holds h0(s-1)  (zeroed at s=0)
        short*       h0w = p ? h0B : h0A;   // receives h0(s)
        const short* h1r = p ? h1B : h1A;   // holds h1(s-2)  (zeroed at s<=1)
        short*       h1w = p ? h1A : h1B;   // receives h1(s-1)

        // ---- ih0 GEMM (pre-barrier; x is read-only cached) ----
        float4v acc_i0 = {0.f, 0.f, 0.f, 0.f};
        if (do0) {
            const short8* Axp = (const short8*)xb + (((size_t)(t0 * BATCH + m_row) * DIN) >> 3) + quad;
            float4v a0 = {0.f,0.f,0.f,0.f}, a1 = {0.f,0.f,0.f,0.f};
#pragma unroll
            for (int kk = 0; kk < 16; ++kk) {
                if (kk & 1) a1 = __builtin_amdgcn_mfma_f32_16x16x32_bf16(Axp[kk * 4], Bi0p[kk * 4], a1, 0, 0, 0);
                else        a0 = __builtin_amdgcn_mfma_f32_16x16x32_bf16(Axp[kk * 4], Bi0p[kk * 4], a0, 0, 0, 0);
            }
            acc_i0 = a0 + a1;
        }

        // ---- grid barrier: all blocks finished superstep s-1 ----
        if (s > 0) {
            const unsigned need = (unsigned)s;
            for (;;) {
                unsigned f = __hip_atomic_load(&flags[tid * 4], __ATOMIC_RELAXED,
                                               __HIP_MEMORY_SCOPE_AGENT);
                unsigned long long bal = __ballot(f >= need);
                if (lane == 0) okv[wave] = (bal + 1ull == 0ull);
                __syncthreads();
                bool all4 = okv[0] && okv[1] && okv[2] && okv[3];
                __syncthreads();
                if (all4) break;
                __builtin_amdgcn_s_sleep(2);
            }
            asm volatile("" ::: "memory");   // no load motion across the barrier
        }

        // ---- bypass loads: A2 <- h0(s-1), C2 <- h1(s-2) (parity buffers) ----
        u64 A2[64];
        u64 C2[64];
        {
            const u64* hp = (const u64*)h0r + (size_t)m_row * (HID / 4) + quad * 2;
            const u64* cp = (const u64*)h1r + (size_t)m_row * (HID / 4) + quad * 2;
#pragma unroll
            for (int kk = 0; kk < 32; ++kk) {
                A2[2 * kk]     = __hip_atomic_load(hp + kk * 8,     __ATOMIC_RELAXED, __HIP_MEMORY_SCOPE_AGENT);
                A2[2 * kk + 1] = __hip_atomic_load(hp + kk * 8 + 1, __ATOMIC_RELAXED, __HIP_MEMORY_SCOPE_AGENT);
            }
#pragma unroll
            for (int kk = 0; kk < 32; ++kk) {
                C2[2 * kk]     = __hip_atomic_load(cp + kk * 8,     __ATOMIC_RELAXED, __HIP_MEMORY_SCOPE_AGENT);
                C2[2 * kk + 1] = __hip_atomic_load(cp + kk * 8 + 1, __ATOMIC_RELAXED, __HIP_MEMORY_SCOPE_AGENT);
            }
        }

        // ---- shared-A GEMMs: hh0 (A2 x Whh0) and ih1 (A2 x Wih1) ----
        float4v acc_h0 = {0.f,0.f,0.f,0.f}, acc_i1 = {0.f,0.f,0.f,0.f};
        {
            float4v h0a = {0.f,0.f,0.f,0.f}, h0b = {0.f,0.f,0.f,0.f};
            float4v i1a = {0.f,0.f,0.f,0.f}, i1b = {0.f,0.f,0.f,0.f};
#pragma unroll
            for (int kk = 0; kk < 32; ++kk) {
                Frag fa;
                fa.u[0] = A2[2 * kk]; fa.u[1] = A2[2 * kk + 1];
                if (do0) {
                    if (kk & 1) h0b = __builtin_amdgcn_mfma_f32_16x16x32_bf16(fa.s, Bh0p[kk * 4], h0b, 0, 0, 0);
                    else        h0a = __builtin_amdgcn_mfma_f32_16x16x32_bf16(fa.s, Bh0p[kk * 4], h0a, 0, 0, 0);
                }
                if (kk & 1) i1b = __builtin_amdgcn_mfma_f32_16x16x32_bf16(fa.s, Bi1p[kk * 4], i1b, 0, 0, 0);
                else        i1a = __builtin_amdgcn_mfma_f32_16x16x32_bf16(fa.s, Bi1p[kk * 4], i1a, 0, 0, 0);
            }
            acc_h0 = h0a + h0b;
            acc_i1 = i1a + i1b;
        }

        // ================= layer-0 BN + gates (C2 latency hides under this) ====
        if (do0) {
            float s1h = acc_h0[0] + acc_h0[1] + acc_h0[2] + acc_h0[3];
            float s2h = acc_h0[0]*acc_h0[0] + acc_h0[1]*acc_h0[1] + acc_h0[2]*acc_h0[2] + acc_h0[3]*acc_h0[3];
            float s1i = acc_i0[0] + acc_i0[1] + acc_i0[2] + acc_i0[3];
            float s2i = acc_i0[0]*acc_i0[0] + acc_i0[1]*acc_i0[1] + acc_i0[2]*acc_i0[2] + acc_i0[3]*acc_i0[3];
            s1h += __shfl_xor(s1h, 16); s1h += __shfl_xor(s1h, 32);
            s2h += __shfl_xor(s2h, 16); s2h += __shfl_xor(s2h, 32);
            s1i += __shfl_xor(s1i, 16); s1i += __shfl_xor(s1i, 32);
            s2i += __shfl_xor(s2i, 16); s2i += __shfl_xor(s2i, 32);
            if (quad == 0) {
                red_h[wave][nidx][0] = s1h; red_h[wave][nidx][1] = s2h;
                red_i[wave][nidx][0] = s1i; red_i[wave][nidx][1] = s2i;
            }
            __syncthreads();
            float th = 0.f, qh = 0.f, ti = 0.f, qi = 0.f;
#pragma unroll
            for (int w = 0; w < 4; ++w) {
                th += red_h[w][nidx][0]; qh += red_h[w][nidx][1];
                ti += red_i[w][nidx][0]; qi += red_i[w][nidx][1];
            }
            float muh = th * inv64, vah = qh * inv64 - muh * muh;
            float mui = ti * inv64, vai = qi * inv64 - mui * mui;
            float rsh = rsqrtf(vah + 1e-5f), rsi = rsqrtf(vai + 1e-5f);
#pragma unroll
            for (int r = 0; r < 4; ++r) {
                float sv = ghh0v * (acc_h0[r] - muh) * rsh + bthh0v
                         + gih0v * (acc_i0[r] - mui) * rsi + btih0v + bb0v;
                st_s[wave][quad * 4 + r][nidx] = sv;
            }
            __syncthreads();

            float fv = st_s[wave][mc][jc];
            float iv = st_s[wave][mc][4 + jc];
            float ov = st_s[wave][mc][8 + jc];
            float gv = st_s[wave][mc][12 + jc];
            float c1 = sigmoidf_(fv) * c0_st + sigmoidf_(iv) * tanhf_(gv);

            float cs = c1, cq = c1 * c1;
            cs += __shfl_xor(cs, 1); cs += __shfl_xor(cs, 2);
            cs += __shfl_xor(cs, 4); cs += __shfl_xor(cs, 8);
            cq += __shfl_xor(cq, 1); cq += __shfl_xor(cq, 2);
            cq += __shfl_xor(cq, 4); cq += __shfl_xor(cq, 8);
            if (mc == 0) { red_c[wave][jc][0] = cs; red_c[wave][jc][1] = cq; }
            __syncthreads();
            float tc = 0.f, qc = 0.f;
#pragma unroll
            for (int w = 0; w < 4; ++w) { tc += red_c[w][jc][0]; qc += red_c[w][jc][1]; }
            float muc = tc * inv64, vac = qc * inv64 - muc * muc;
            float bnc = gc0v * (c1 - muc) * rsqrtf(vac + 1e-5f) + btc0v;
            float h1v = sigmoidf_(ov) * tanhf_(bnc);

            bool mk = (t0 < len_c);
            h0_st = mk ? h1v : h0_st;
            c0_st = mk ? c1  : c0_st;

            // publish h0(t0) to parity buffer (bypass store -> coherence point)
            short hv = f2bf(h0_st);
            __hip_atomic_store(&h0w[m_cg * HID + j_g], hv,
                               __ATOMIC_RELAXED, __HIP_MEMORY_SCOPE_AGENT);
        }

        // ---- hh1 GEMM (C2 x Whh1), loads long in flight ----
        float4v acc_h1 = {0.f,0.f,0.f,0.f};
        {
            float4v ha = {0.f,0.f,0.f,0.f}, hb = {0.f,0.f,0.f,0.f};
            float4v hc = {0.f,0.f,0.f,0.f}, hd = {0.f,0.f,0.f,0.f};
#pragma unroll
            for (int kk = 0; kk < 32; ++kk) {
                Frag fa;
                fa.u[0] = C2[2 * kk]; fa.u[1] = C2[2 * kk + 1];
                switch (kk & 3) {
                    case 0:  ha = __builtin_amdgcn_mfma_f32_16x16x32_bf16(fa.s, Bh1p[kk * 4], ha, 0, 0, 0); break;
                    case 1:  hb = __builtin_amdgcn_mfma_f32_16x16x32_bf16(fa.s, Bh1p[kk * 4], hb, 0, 0, 0); break;
                    case 2:  hc = __builtin_amdgcn_mfma_f32_16x16x32_bf16(fa.s, Bh1p[kk * 4], hc, 0, 0, 0); break;
                    default: hd = __builtin_amdgcn_mfma_f32_16x16x32_bf16(fa.s, Bh1p[kk * 4], hd, 0, 0, 0); break;
                }
            }
            acc_h1 = (ha + hb) + (hc + hd);
        }

        // ================= layer-1 BN + gates =================
        if (do1) {
            float s1h = acc_h1[0] + acc_h1[1] + acc_h1[2] + acc_h1[3];
            float s2h = acc_h1[0]*acc_h1[0] + acc_h1[1]*acc_h1[1] + acc_h1[2]*acc_h1[2] + acc_h1[3]*acc_h1[3];
            float s1i = acc_i1[0] + acc_i1[1] + acc_i1[2] + acc_i1[3];
            float s2i = acc_i1[0]*acc_i1[0] + acc_i1[1]*acc_i1[1] + acc_i1[2]*acc_i1[2] + acc_i1[3]*acc_i1[3];
            s1h += __shfl_xor(s1h, 16); s1h += __shfl_xor(s1h, 32);
            s2h += __shfl_xor(s2h, 16); s2h += __shfl_xor(s2h, 32);
            s1i += __shfl_xor(s1i, 16); s1i += __shfl_xor(s1i, 32);
            s2i += __shfl_xor(s2i, 16); s2i += __shfl_xor(s2i, 32);
            if (quad == 0) {
                red_h[wave][nidx][0] = s1h; red_h[wave][nidx][1] = s2h;
                red_i[wave][nidx][0] = s1i; red_i[wave][nidx][1] = s2i;
            }
            __syncthreads();
            float th = 0.f, qh = 0.f, ti = 0.f, qi = 0.f;
#pragma unroll
            for (int w = 0; w < 4; ++w) {
                th += red_h[w][nidx][0]; qh += red_h[w][nidx][1];
                ti += red_i[w][nidx][0]; qi += red_i[w][nidx][1];
            }
            float muh = th * inv64, vah = qh * inv64 - muh * muh;
            float mui = ti * inv64, vai = qi * inv64 - mui * mui;
            float rsh = rsqrtf(vah + 1e-5f), rsi = rsqrtf(vai + 1e-5f);
#pragma unroll
            for (int r = 0; r < 4; ++r) {
                float sv = ghh1v * (acc_h1[r] - muh) * rsh + bthh1v
                         + gih1v * (acc_i1[r] - mui) * rsi + btih1v + bb1v;
                st_s[wave][quad * 4 + r][nidx] = sv;
            }
            __syncthreads();

            float fv = st_s[wave][mc][jc];
            float iv = st_s[wave][mc][4 + jc];
            float ov = st_s[wave][mc][8 + jc];
            float gv = st_s[wave][mc][12 + jc];
            float c1 = sigmoidf_(fv) * c1_st + sigmoidf_(iv) * tanhf_(gv);

            float cs = c1, cq = c1 * c1;
            cs += __shfl_xor(cs, 1); cs += __shfl_xor(cs, 2);
            cs += __shfl_xor(cs, 4); cs += __shfl_xor(cs, 8);
            cq += __shfl_xor(cq, 1); cq += __shfl_xor(cq, 2);
            cq += __shfl_xor(cq, 4); cq += __shfl_xor(cq, 8);
            if (mc == 0) { red_c[wave][jc][0] = cs; red_c[wave][jc][1] = cq; }
            __syncthreads();
            float tc = 0.f, qc = 0.f;
#pragma unroll
            for (int w = 0; w < 4; ++w) { tc += red_c[w][jc][0]; qc += red_c[w][jc][1]; }
            float muc = tc * inv64, vac = qc * inv64 - muc * muc;
            float bnc = gc1v * (c1 - muc) * rsqrtf(vac + 1e-5f) + btc1v;
            float h1v = sigmoidf_(ov) * tanhf_(bnc);

            bool mk = (t1 < len_c);
            h1_st = mk ? h1v : h1_st;
            c1_st = mk ? c1  : c1_st;

            // publish h1(t1) to parity buffer + fp32 y output
            short hv = f2bf(h1_st);
            __hip_atomic_store(&h1w[m_cg * HID + j_g], hv,
                               __ATOMIC_RELAXED, __HIP_MEMORY_SCOPE_AGENT);
            out[(size_t)(t1 * BATCH + m_cg) * HID + j_g] = h1_st;
        }

        // ---- arrive: drain own stores, then flag (no wbl2, no inv) ----
        __builtin_amdgcn_s_waitcnt(0);
        __syncthreads();
        if (tid == 0)
            __hip_atomic_store(&flags[wg * 4], (unsigned)(s + 1), __ATOMIC_RELAXED,
                               __HIP_MEMORY_SCOPE_AGENT);
    }

    // final h_n / c_n for both layers, straight from registers
    {
        const size_t ybase = (size_t)T_STEPS * BATCH * HID;
        const size_t off = (size_t)m_cg * HID + j_g;
        out[ybase + 0 * (size_t)BATCH * HID + off] = h0_st;
        out[ybase + 1 * (size_t)BATCH * HID + off] = h1_st;
        out[ybase + 2 * (size_t)BATCH * HID + off] = c0_st;
        out[ybase + 3 * (size_t)BATCH * HID + off] = c1_st;
    }
}

// ---------------- launch ----------------
extern "C" void kernel_launch(void* const* d_in, const int* in_sizes, int n_in,
                              void* d_out, int out_size, void* d_ws, size_t ws_size,
                              hipStream_t stream)
{
    const float* x      = (const float*)d_in[0];
    const int*   length = (const int*)  d_in[1];
    const float* w_ih0  = (const float*)d_in[2];
    const float* w_hh0  = (const float*)d_in[3];
    const float* b0     = (const float*)d_in[4];
    const float* g_ih0  = (const float*)d_in[5];
    const float* bt_ih0 = (const float*)d_in[6];
    const float* g_hh0  = (const float*)d_in[7];
    const float* bt_hh0 = (const float*)d_in[8];
    const float* g_c0   = (const float*)d_in[9];
    const float* bt_c0  = (const float*)d_in[10];
    const float* w_ih1  = (const float*)d_in[11];
    const float* w_hh1  = (const float*)d_in[12];
    const float* b1     = (const float*)d_in[13];
    const float* g_ih1  = (const float*)d_in[14];
    const float* bt_ih1 = (const float*)d_in[15];
    const float* g_hh1  = (const float*)d_in[16];
    const float* bt_hh1 = (const float*)d_in[17];
    const float* g_c1   = (const float*)d_in[18];
    const float* bt_c1  = (const float*)d_in[19];

    char* ws = (char*)d_ws;
    // workspace layout (16B-aligned; total 46,665,728 B -- inside the
    // PROVEN 80,220,160 B budget of the passing kernel)
    unsigned* flags = (unsigned*)(ws + 0);            // 4096 B (256 flags, 16B stride)
    short* h0A   = (short*)(ws + 4096);               // 131072 B
    short* h0B   = (short*)(ws + 135168);             // 131072 B
    short* h1A   = (short*)(ws + 266240);             // 131072 B
    short* h1B   = (short*)(ws + 397312);             // 131072 B
    // ---- end of zeroed region: 528384 (identical to proven kernel) ----
    short* xb    = (short*)(ws + 528384);             // 16,777,216 B
    short* wih0T = (short*)(ws + 17305600);           //  4,194,304 B
    short* whh0T = (short*)(ws + 21499904);           //  8,388,608 B
    short* wih1T = (short*)(ws + 29888512);           //  8,388,608 B
    short* whh1T = (short*)(ws + 38277120);           //  8,388,608 B
    // total footprint: 46,665,728 bytes

    // zero flags + h parity buffers (harness re-poisons ws each timed launch)
    (void)hipMemsetAsync(ws, 0, 528384, stream);

    cvt_bf16_kernel<<<2048, 256, 0, stream>>>(x, xb, T_STEPS * BATCH * DIN);

    dim3 tb(32, 8);
    transpose_bf16_kernel<<<dim3(NCOLS / 32, DIN / 32), tb, 0, stream>>>(w_ih0, wih0T, DIN, NCOLS);
    transpose_bf16_kernel<<<dim3(NCOLS / 32, HID / 32), tb, 0, stream>>>(w_hh0, whh0T, HID, NCOLS);
    transpose_bf16_kernel<<<dim3(NCOLS / 32, HID / 32), tb, 0, stream>>>(w_ih1, wih1T, HID, NCOLS);
    transpose_bf16_kernel<<<dim3(NCOLS / 32, HID / 32), tb, 0, stream>>>(w_hh1, whh1T, HID, NCOLS);

    lstm_persist<<<NBLK, TPB, 0, stream>>>(
        length,
        b0, g_ih0, bt_ih0, g_hh0, bt_hh0, g_c0, bt_c0,
        b1, g_ih1, bt_ih1, g_hh1, bt_hh1, g_c1, bt_c1,
        xb, wih0T, whh0T, wih1T, whh1T,
        h0A, h0B, h1A, h1B,
        flags,
        (float*)d_out);
}

// Round 5
// 7029.926 us; speedup vs baseline: 1.3915x; 1.3915x over previous
//
#include <hip/hip_runtime.h>

// ---------------- problem constants ----------------
#define T_STEPS 256
#define BATCH   64
#define DIN     512
#define HID     1024
#define NCOLS   4096   // 4*HID
#define NBLK    256    // persistent blocks (1 per CU)
#define TPB     256    // 4 waves

typedef __attribute__((ext_vector_type(8))) short short8;
typedef __attribute__((ext_vector_type(4))) float float4v;
typedef unsigned long long u64;

union Frag { u64 u[2]; short8 s; };

__device__ __forceinline__ short f2bf(float x) {
    unsigned u = __float_as_uint(x);
    u += 0x7FFFu + ((u >> 16) & 1u);   // RNE
    return (short)(u >> 16);
}
__device__ __forceinline__ float sigmoidf_(float x) { return 1.0f / (1.0f + __expf(-x)); }
__device__ __forceinline__ float tanhf_(float x)    { return 1.0f - 2.0f / (__expf(2.0f * x) + 1.0f); }

// ---------------- prologue kernels ----------------
__global__ void cvt_bf16_kernel(const float* __restrict__ src, short* __restrict__ dst, int n) {
    int i = blockIdx.x * blockDim.x + threadIdx.x;
    int stride = gridDim.x * blockDim.x;
    for (; i < n; i += stride) dst[i] = f2bf(src[i]);
}

// src: R x C fp32 row-major -> dst: C x R bf16 row-major
__global__ void transpose_bf16_kernel(const float* __restrict__ src, short* __restrict__ dst,
                                      int R, int C) {
    __shared__ float tile[32][33];
    int tx = threadIdx.x, ty = threadIdx.y;
    int r0 = blockIdx.y * 32, c0 = blockIdx.x * 32;
#pragma unroll
    for (int i = 0; i < 32; i += 8)
        tile[ty + i][tx] = src[(size_t)(r0 + ty + i) * C + (c0 + tx)];
    __syncthreads();
#pragma unroll
    for (int i = 0; i < 32; i += 8)
        dst[(size_t)(c0 + ty + i) * R + (r0 + tx)] = f2bf(tile[tx][ty + i]);
}

// ---------------- fused persistent LSTM, layer-pipelined ----------------
// Superstep s (0..256): layer0 computes t0=s, layer1 computes t1=s-1.
// One grid barrier per superstep (257 instead of 512).
//
// Round-3 (passing, 9.7ms) regression cause: streaming all four weight
// matrices per superstep = 3.6 MB/XCD working set > 4 MiB L2 -> thrash
// (FETCH_SIZE 1.8 GB). Round-4 fix attempt (112 KB dynamic LDS) exceeded
// the 64 KB block limit -> launch failed silently (out stayed zero).
//
// Round-5 fix, conservative: STATIC LDS only (53.5 KB total, no opt-in):
//  - Wih0 (16 KB) + Whh1 (32 KB) staged once in fragment order;
//    in-loop read = contiguous 1024 B per wave -> conflict-free.
//  - Whh0 + Wih1 remain cached-streamed (as the round-3 passing kernel),
//    but the streamed per-XCD set is now 32 x 64 KB = 2 MB -> L2-resident.
//
// Communication substrate = byte-for-byte the proven 7.3ms kernel's:
//  - h state in parity double-buffers (h0A/B, h1A/B), memset-zeroed
//    (correct h(-1)=0 -> BN(0)=beta boundary).
//  - writes: relaxed AGENT-scope atomic stores, drained with s_waitcnt(0)
//    + __syncthreads before the flag store.
//  - reads: relaxed AGENT-scope atomic loads (bypass L1/L2).
//  - parity (p = s&1): read h0(s-1) from buf0[1-p], write h0(s) to buf0[p];
//    read h1(s-2) from buf1[p], write h1(s-1) to buf1[1-p].
//  - A2 = h0(s-1) feeds BOTH hh0 and ih1: one bypass stream, two GEMMs.
// Workspace 46.7 MB -- inside the proven 80.2 MB budget.
__global__ __launch_bounds__(TPB, 1) void lstm_persist(
    const int* __restrict__ length,
    const float* __restrict__ b0,  const float* __restrict__ g_ih0, const float* __restrict__ bt_ih0,
    const float* __restrict__ g_hh0, const float* __restrict__ bt_hh0,
    const float* __restrict__ g_c0,  const float* __restrict__ bt_c0,
    const float* __restrict__ b1,  const float* __restrict__ g_ih1, const float* __restrict__ bt_ih1,
    const float* __restrict__ g_hh1, const float* __restrict__ bt_hh1,
    const float* __restrict__ g_c1,  const float* __restrict__ bt_c1,
    const short* __restrict__ xb,
    const short* __restrict__ wih0T, const short* __restrict__ whh0T,
    const short* __restrict__ wih1T, const short* __restrict__ whh1T,
    short* __restrict__ h0A, short* __restrict__ h0B,
    short* __restrict__ h1A, short* __restrict__ h1B,
    unsigned* __restrict__ flags,
    float* __restrict__ out)
{
    const int wg   = blockIdx.x;
    const int tid  = threadIdx.x;
    const int wave = tid >> 6;
    const int lane = tid & 63;
    const int nidx = lane & 15;
    const int quad = lane >> 4;

    __shared__ short8 Li0s[1024];       // Wih0 slice, 16 KB (frag order)
    __shared__ short8 Lh1s[2048];       // Whh1 slice, 32 KB (frag order)
    __shared__ float st_s[4][16][17];   // per-wave 16x16 s tile (+pad)
    __shared__ float red_h[4][16][2];   // per-wave column (sum,sumsq) hh
    __shared__ float red_i[4][16][2];   // ... ih
    __shared__ float red_c[4][4][2];    // per-wave (sum,sumsq) for c, 4 j's
    __shared__ unsigned okv[4];         // barrier poll combine

    const int jj   = nidx & 3;
    const int gidx = nidx >> 2;
    const int ncol = wg * 4 + jj + gidx * HID;   // s-space column 0..4095
    const int m_row = wave * 16 + nidx;          // A-fragment batch row

    const int mc   = lane & 15;                  // c-phase: row within wave
    const int jc   = quad;                       // c-phase: which of 4 j's
    const int m_cg = wave * 16 + mc;
    const int j_g  = wg * 4 + jc;
    const int len_c = length[m_cg];
    const float inv64 = 1.0f / 64.0f;

    // ---- one-time LDS staging: Wih0 + Whh1 fragments ----
    // layout: frag f = e*16 + n, where e = column short8-index (quad + 4*kk),
    // n = nidx (selects ncol_n). Coalesced global reads (consecutive e).
    for (int idx = tid; idx < 1024; idx += TPB) {
        int e = idx & 63, n = idx >> 6;
        int ncol_n = wg * 4 + (n & 3) + (n >> 2) * HID;
        Li0s[e * 16 + n] = ((const short8*)wih0T)[(size_t)ncol_n * 64 + e];
    }
    for (int idx = tid; idx < 2048; idx += TPB) {
        int e = idx & 127, n = idx >> 7;
        int ncol_n = wg * 4 + (n & 3) + (n >> 2) * HID;
        Lh1s[e * 16 + n] = ((const short8*)whh1T)[(size_t)ncol_n * 128 + e];
    }
    __syncthreads();

    const int b_off = quad * 16 + nidx;   // fragment offset: idx = kk*64 + b_off

    // B-fragment base pointers for the two STREAMED matrices (L2-resident:
    // 2 MB/XCD total)
    const short8* Bh0p = (const short8*)whh0T + (size_t)ncol * (HID / 8) + quad;
    const short8* Bi1p = (const short8*)wih1T + (size_t)ncol * (HID / 8) + quad;

    // per-layer BN / bias params (registers for the whole run)
    const float gih0v = g_ih0[ncol], btih0v = bt_ih0[ncol];
    const float ghh0v = g_hh0[ncol], bthh0v = bt_hh0[ncol], bb0v = b0[ncol];
    const float gc0v  = g_c0[j_g],   btc0v  = bt_c0[j_g];
    const float gih1v = g_ih1[ncol], btih1v = bt_ih1[ncol];
    const float ghh1v = g_hh1[ncol], bthh1v = bt_hh1[ncol], bb1v = b1[ncol];
    const float gc1v  = g_c1[j_g],   btc1v  = bt_c1[j_g];

    float h0_st = 0.f, c0_st = 0.f, h1_st = 0.f, c1_st = 0.f;

#pragma unroll 1
    for (int s = 0; s <= T_STEPS; ++s) {
        const bool do0 = (s < T_STEPS);   // layer0 active (t0 = s)
        const bool do1 = (s >= 1);        // layer1 active (t1 = s-1)
        const int t0 = s, t1 = s - 1;
        const int p  = s & 1;
        const short* h0r = p ? h0A : h0B;   // holds h0(s-1)  (zeroed at s=0)
        short*       h0w = p ? h0B : h0A;   // receives h0(s)
        const short* h1r = p ? h1B : h1A;   // holds h1(s-2)  (zeroed at s<=1)
        short*       h1w = p ? h1A : h1B;   // receives h1(s-1)

        // ---- ih0 GEMM (pre-barrier; x cached, B from LDS) ----
        float4v acc_i0 = {0.f, 0.f, 0.f, 0.f};
        if (do0) {
            const short8* Axp = (const short8*)xb + (((size_t)(t0 * BATCH + m_row) * DIN) >> 3) + quad;
            float4v a0 = {0.f,0.f,0.f,0.f}, a1 = {0.f,0.f,0.f,0.f};
#pragma unroll
            for (int kk = 0; kk < 16; ++kk) {
                short8 b = Li0s[kk * 64 + b_off];
                if (kk & 1) a1 = __builtin_amdgcn_mfma_f32_16x16x32_bf16(Axp[kk * 4], b, a1, 0, 0, 0);
                else        a0 = __builtin_amdgcn_mfma_f32_16x16x32_bf16(Axp[kk * 4], b, a0, 0, 0, 0);
            }
            acc_i0 = a0 + a1;
        }

        // ---- grid barrier: all blocks finished superstep s-1 ----
        if (s > 0) {
            const unsigned need = (unsigned)s;
            for (;;) {
                unsigned f = __hip_atomic_load(&flags[tid * 4], __ATOMIC_RELAXED,
                                               __HIP_MEMORY_SCOPE_AGENT);
                unsigned long long bal = __ballot(f >= need);
                if (lane == 0) okv[wave] = (bal + 1ull == 0ull);
                __syncthreads();
                bool all4 = okv[0] && okv[1] && okv[2] && okv[3];
                __syncthreads();
                if (all4) break;
                __builtin_amdgcn_s_sleep(2);
            }
            asm volatile("" ::: "memory");   // no load motion across the barrier
        }

        // ---- bypass loads: A2 <- h0(s-1), C2 <- h1(s-2) (parity buffers) ----
        u64 A2[64];
        u64 C2[64];
        {
            const u64* hp = (const u64*)h0r + (size_t)m_row * (HID / 4) + quad * 2;
            const u64* cp = (const u64*)h1r + (size_t)m_row * (HID / 4) + quad * 2;
#pragma unroll
            for (int kk = 0; kk < 32; ++kk) {
                A2[2 * kk]     = __hip_atomic_load(hp + kk * 8,     __ATOMIC_RELAXED, __HIP_MEMORY_SCOPE_AGENT);
                A2[2 * kk + 1] = __hip_atomic_load(hp + kk * 8 + 1, __ATOMIC_RELAXED, __HIP_MEMORY_SCOPE_AGENT);
            }
#pragma unroll
            for (int kk = 0; kk < 32; ++kk) {
                C2[2 * kk]     = __hip_atomic_load(cp + kk * 8,     __ATOMIC_RELAXED, __HIP_MEMORY_SCOPE_AGENT);
                C2[2 * kk + 1] = __hip_atomic_load(cp + kk * 8 + 1, __ATOMIC_RELAXED, __HIP_MEMORY_SCOPE_AGENT);
            }
        }

        // ---- shared-A GEMMs: hh0 (A2 x Whh0) and ih1 (A2 x Wih1), B streamed (L2) ----
        float4v acc_h0 = {0.f,0.f,0.f,0.f}, acc_i1 = {0.f,0.f,0.f,0.f};
        {
            float4v h0a = {0.f,0.f,0.f,0.f}, h0b = {0.f,0.f,0.f,0.f};
            float4v i1a = {0.f,0.f,0.f,0.f}, i1b = {0.f,0.f,0.f,0.f};
#pragma unroll
            for (int kk = 0; kk < 32; ++kk) {
                Frag fa;
                fa.u[0] = A2[2 * kk]; fa.u[1] = A2[2 * kk + 1];
                if (do0) {
                    if (kk & 1) h0b = __builtin_amdgcn_mfma_f32_16x16x32_bf16(fa.s, Bh0p[kk * 4], h0b, 0, 0, 0);
                    else        h0a = __builtin_amdgcn_mfma_f32_16x16x32_bf16(fa.s, Bh0p[kk * 4], h0a, 0, 0, 0);
                }
                if (kk & 1) i1b = __builtin_amdgcn_mfma_f32_16x16x32_bf16(fa.s, Bi1p[kk * 4], i1b, 0, 0, 0);
                else        i1a = __builtin_amdgcn_mfma_f32_16x16x32_bf16(fa.s, Bi1p[kk * 4], i1a, 0, 0, 0);
            }
            acc_h0 = h0a + h0b;
            acc_i1 = i1a + i1b;
        }

        // ================= layer-0 BN + gates (C2 latency hides here) ====
        if (do0) {
            float s1h = acc_h0[0] + acc_h0[1] + acc_h0[2] + acc_h0[3];
            float s2h = acc_h0[0]*acc_h0[0] + acc_h0[1]*acc_h0[1] + acc_h0[2]*acc_h0[2] + acc_h0[3]*acc_h0[3];
            float s1i = acc_i0[0] + acc_i0[1] + acc_i0[2] + acc_i0[3];
            float s2i = acc_i0[0]*acc_i0[0] + acc_i0[1]*acc_i0[1] + acc_i0[2]*acc_i0[2] + acc_i0[3]*acc_i0[3];
            s1h += __shfl_xor(s1h, 16); s1h += __shfl_xor(s1h, 32);
            s2h += __shfl_xor(s2h, 16); s2h += __shfl_xor(s2h, 32);
            s1i += __shfl_xor(s1i, 16); s1i += __shfl_xor(s1i, 32);
            s2i += __shfl_xor(s2i, 16); s2i += __shfl_xor(s2i, 32);
            if (quad == 0) {
                red_h[wave][nidx][0] = s1h; red_h[wave][nidx][1] = s2h;
                red_i[wave][nidx][0] = s1i; red_i[wave][nidx][1] = s2i;
            }
            __syncthreads();
            float th = 0.f, qh = 0.f, ti = 0.f, qi = 0.f;
#pragma unroll
            for (int w = 0; w < 4; ++w) {
                th += red_h[w][nidx][0]; qh += red_h[w][nidx][1];
                ti += red_i[w][nidx][0]; qi += red_i[w][nidx][1];
            }
            float muh = th * inv64, vah = qh * inv64 - muh * muh;
            float mui = ti * inv64, vai = qi * inv64 - mui * mui;
            float rsh = rsqrtf(vah + 1e-5f), rsi = rsqrtf(vai + 1e-5f);
#pragma unroll
            for (int r = 0; r < 4; ++r) {
                float sv = ghh0v * (acc_h0[r] - muh) * rsh + bthh0v
                         + gih0v * (acc_i0[r] - mui) * rsi + btih0v + bb0v;
                st_s[wave][quad * 4 + r][nidx] = sv;
            }
            __syncthreads();

            float fv = st_s[wave][mc][jc];
            float iv = st_s[wave][mc][4 + jc];
            float ov = st_s[wave][mc][8 + jc];
            float gv = st_s[wave][mc][12 + jc];
            float c1 = sigmoidf_(fv) * c0_st + sigmoidf_(iv) * tanhf_(gv);

            float cs = c1, cq = c1 * c1;
            cs += __shfl_xor(cs, 1); cs += __shfl_xor(cs, 2);
            cs += __shfl_xor(cs, 4); cs += __shfl_xor(cs, 8);
            cq += __shfl_xor(cq, 1); cq += __shfl_xor(cq, 2);
            cq += __shfl_xor(cq, 4); cq += __shfl_xor(cq, 8);
            if (mc == 0) { red_c[wave][jc][0] = cs; red_c[wave][jc][1] = cq; }
            __syncthreads();
            float tc = 0.f, qc = 0.f;
#pragma unroll
            for (int w = 0; w < 4; ++w) { tc += red_c[w][jc][0]; qc += red_c[w][jc][1]; }
            float muc = tc * inv64, vac = qc * inv64 - muc * muc;
            float bnc = gc0v * (c1 - muc) * rsqrtf(vac + 1e-5f) + btc0v;
            float h1v = sigmoidf_(ov) * tanhf_(bnc);

            bool mk = (t0 < len_c);
            h0_st = mk ? h1v : h0_st;
            c0_st = mk ? c1  : c0_st;

            // publish h0(t0) to parity buffer (bypass store -> coherence point)
            short hv = f2bf(h0_st);
            __hip_atomic_store(&h0w[m_cg * HID + j_g], hv,
                               __ATOMIC_RELAXED, __HIP_MEMORY_SCOPE_AGENT);
        }

        // ---- hh1 GEMM (C2 x Whh1), B from LDS, loads long in flight ----
        float4v acc_h1 = {0.f,0.f,0.f,0.f};
        {
            float4v ha = {0.f,0.f,0.f,0.f}, hb = {0.f,0.f,0.f,0.f};
            float4v hc = {0.f,0.f,0.f,0.f}, hd = {0.f,0.f,0.f,0.f};
#pragma unroll
            for (int kk = 0; kk < 32; ++kk) {
                Frag fa;
                fa.u[0] = C2[2 * kk]; fa.u[1] = C2[2 * kk + 1];
                short8 bh = Lh1s[kk * 64 + b_off];
                switch (kk & 3) {
                    case 0:  ha = __builtin_amdgcn_mfma_f32_16x16x32_bf16(fa.s, bh, ha, 0, 0, 0); break;
                    case 1:  hb = __builtin_amdgcn_mfma_f32_16x16x32_bf16(fa.s, bh, hb, 0, 0, 0); break;
                    case 2:  hc = __builtin_amdgcn_mfma_f32_16x16x32_bf16(fa.s, bh, hc, 0, 0, 0); break;
                    default: hd = __builtin_amdgcn_mfma_f32_16x16x32_bf16(fa.s, bh, hd, 0, 0, 0); break;
                }
            }
            acc_h1 = (ha + hb) + (hc + hd);
        }

        // ================= layer-1 BN + gates =================
        if (do1) {
            float s1h = acc_h1[0] + acc_h1[1] + acc_h1[2] + acc_h1[3];
            float s2h = acc_h1[0]*acc_h1[0] + acc_h1[1]*acc_h1[1] + acc_h1[2]*acc_h1[2] + acc_h1[3]*acc_h1[3];
            float s1i = acc_i1[0] + acc_i1[1] + acc_i1[2] + acc_i1[3];
            float s2i = acc_i1[0]*acc_i1[0] + acc_i1[1]*acc_i1[1] + acc_i1[2]*acc_i1[2] + acc_i1[3]*acc_i1[3];
            s1h += __shfl_xor(s1h, 16); s1h += __shfl_xor(s1h, 32);
            s2h += __shfl_xor(s2h, 16); s2h += __shfl_xor(s2h, 32);
            s1i += __shfl_xor(s1i, 16); s1i += __shfl_xor(s1i, 32);
            s2i += __shfl_xor(s2i, 16); s2i += __shfl_xor(s2i, 32);
            if (quad == 0) {
                red_h[wave][nidx][0] = s1h; red_h[wave][nidx][1] = s2h;
                red_i[wave][nidx][0] = s1i; red_i[wave][nidx][1] = s2i;
            }
            __syncthreads();
            float th = 0.f, qh = 0.f, ti = 0.f, qi = 0.f;
#pragma unroll
            for (int w = 0; w < 4; ++w) {
                th += red_h[w][nidx][0]; qh += red_h[w][nidx][1];
                ti += red_i[w][nidx][0]; qi += red_i[w][nidx][1];
            }
            float muh = th * inv64, vah = qh * inv64 - muh * muh;
            float mui = ti * inv64, vai = qi * inv64 - mui * mui;
            float rsh = rsqrtf(vah + 1e-5f), rsi = rsqrtf(vai + 1e-5f);
#pragma unroll
            for (int r = 0; r < 4; ++r) {
                float sv = ghh1v * (acc_h1[r] - muh) * rsh + bthh1v
                         + gih1v * (acc_i1[r] - mui) * rsi + btih1v + bb1v;
                st_s[wave][quad * 4 + r][nidx] = sv;
            }
            __syncthreads();

            float fv = st_s[wave][mc][jc];
            float iv = st_s[wave][mc][4 + jc];
            float ov = st_s[wave][mc][8 + jc];
            float gv = st_s[wave][mc][12 + jc];
            float c1 = sigmoidf_(fv) * c1_st + sigmoidf_(iv) * tanhf_(gv);

            float cs = c1, cq = c1 * c1;
            cs += __shfl_xor(cs, 1); cs += __shfl_xor(cs, 2);
            cs += __shfl_xor(cs, 4); cs += __shfl_xor(cs, 8);
            cq += __shfl_xor(cq, 1); cq += __shfl_xor(cq, 2);
            cq += __shfl_xor(cq, 4); cq += __shfl_xor(cq, 8);
            if (mc == 0) { red_c[wave][jc][0] = cs; red_c[wave][jc][1] = cq; }
            __syncthreads();
            float tc = 0.f, qc = 0.f;
#pragma unroll
            for (int w = 0; w < 4; ++w) { tc += red_c[w][jc][0]; qc += red_c[w][jc][1]; }
            float muc = tc * inv64, vac = qc * inv64 - muc * muc;
            float bnc = gc1v * (c1 - muc) * rsqrtf(vac + 1e-5f) + btc1v;
            float h1v = sigmoidf_(ov) * tanhf_(bnc);

            bool mk = (t1 < len_c);
            h1_st = mk ? h1v : h1_st;
            c1_st = mk ? c1  : c1_st;

            // publish h1(t1) to parity buffer + fp32 y output
            short hv = f2bf(h1_st);
            __hip_atomic_store(&h1w[m_cg * HID + j_g], hv,
                               __ATOMIC_RELAXED, __HIP_MEMORY_SCOPE_AGENT);
            out[(size_t)(t1 * BATCH + m_cg) * HID + j_g] = h1_st;
        }

        // ---- arrive: drain own stores, then flag (no wbl2, no inv) ----
        __builtin_amdgcn_s_waitcnt(0);
        __syncthreads();
        if (tid == 0)
            __hip_atomic_store(&flags[wg * 4], (unsigned)(s + 1), __ATOMIC_RELAXED,
                               __HIP_MEMORY_SCOPE_AGENT);
    }

    // final h_n / c_n for both layers, straight from registers
    {
        const size_t ybase = (size_t)T_STEPS * BATCH * HID;
        const size_t off = (size_t)m_cg * HID + j_g;
        out[ybase + 0 * (size_t)BATCH * HID + off] = h0_st;
        out[ybase + 1 * (size_t)BATCH * HID + off] = h1_st;
        out[ybase + 2 * (size_t)BATCH * HID + off] = c0_st;
        out[ybase + 3 * (size_t)BATCH * HID + off] = c1_st;
    }
}

// ---------------- launch ----------------
extern "C" void kernel_launch(void* const* d_in, const int* in_sizes, int n_in,
                              void* d_out, int out_size, void* d_ws, size_t ws_size,
                              hipStream_t stream)
{
    const float* x      = (const float*)d_in[0];
    const int*   length = (const int*)  d_in[1];
    const float* w_ih0  = (const float*)d_in[2];
    const float* w_hh0  = (const float*)d_in[3];
    const float* b0     = (const float*)d_in[4];
    const float* g_ih0  = (const float*)d_in[5];
    const float* bt_ih0 = (const float*)d_in[6];
    const float* g_hh0  = (const float*)d_in[7];
    const float* bt_hh0 = (const float*)d_in[8];
    const float* g_c0   = (const float*)d_in[9];
    const float* bt_c0  = (const float*)d_in[10];
    const float* w_ih1  = (const float*)d_in[11];
    const float* w_hh1  = (const float*)d_in[12];
    const float* b1     = (const float*)d_in[13];
    const float* g_ih1  = (const float*)d_in[14];
    const float* bt_ih1 = (const float*)d_in[15];
    const float* g_hh1  = (const float*)d_in[16];
    const float* bt_hh1 = (const float*)d_in[17];
    const float* g_c1   = (const float*)d_in[18];
    const float* bt_c1  = (const float*)d_in[19];

    char* ws = (char*)d_ws;
    // workspace layout (16B-aligned; total 46,665,728 B -- inside the
    // PROVEN 80,220,160 B budget of the passing kernel)
    unsigned* flags = (unsigned*)(ws + 0);            // 4096 B (256 flags, 16B stride)
    short* h0A   = (short*)(ws + 4096);               // 131072 B
    short* h0B   = (short*)(ws + 135168);             // 131072 B
    short* h1A   = (short*)(ws + 266240);             // 131072 B
    short* h1B   = (short*)(ws + 397312);             // 131072 B
    // ---- end of zeroed region: 528384 (identical to proven kernel) ----
    short* xb    = (short*)(ws + 528384);             // 16,777,216 B
    short* wih0T = (short*)(ws + 17305600);           //  4,194,304 B
    short* whh0T = (short*)(ws + 21499904);           //  8,388,608 B
    short* wih1T = (short*)(ws + 29888512);           //  8,388,608 B
    short* whh1T = (short*)(ws + 38277120);           //  8,388,608 B
    // total footprint: 46,665,728 bytes

    // zero flags + h parity buffers (harness re-poisons ws each timed launch)
    (void)hipMemsetAsync(ws, 0, 528384, stream);

    cvt_bf16_kernel<<<2048, 256, 0, stream>>>(x, xb, T_STEPS * BATCH * DIN);

    dim3 tb(32, 8);
    transpose_bf16_kernel<<<dim3(NCOLS / 32, DIN / 32), tb, 0, stream>>>(w_ih0, wih0T, DIN, NCOLS);
    transpose_bf16_kernel<<<dim3(NCOLS / 32, HID / 32), tb, 0, stream>>>(w_hh0, whh0T, HID, NCOLS);
    transpose_bf16_kernel<<<dim3(NCOLS / 32, HID / 32), tb, 0, stream>>>(w_ih1, wih1T, HID, NCOLS);
    transpose_bf16_kernel<<<dim3(NCOLS / 32, HID / 32), tb, 0, stream>>>(w_hh1, whh1T, HID, NCOLS);

    lstm_persist<<<NBLK, TPB, 0, stream>>>(
        length,
        b0, g_ih0, bt_ih0, g_hh0, bt_hh0, g_c0, bt_c0,
        b1, g_ih1, bt_ih1, g_hh1, bt_hh1, g_c1, bt_c1,
        xb, wih0T, whh0T, wih1T, whh1T,
        h0A, h0B, h1A, h1B,
        flags,
        (float*)d_out);
}